// Round 16
// baseline (89.564 us; speedup 1.0000x reference)
//
#include <hip/hip_runtime.h>

typedef __attribute__((ext_vector_type(2))) float f32x2;

#define W 4096
#define H 4096
#define NT 128                   // 2 waves per block
#define COLS 512                 // columns per block (4 per thread)
#define SR 16                    // output rows per block strip
#define GROUP 4                  // rows staged per barrier
#define NSTAGE (SR + 14)         // 30 staged rows contribute
#define NG 8                     // 8 groups of 4 (32 slots, last 2 guarded)
#define LW 528                   // floats per staged row: f <-> col c0-8+f
#define RAD 7
#define PEND 18                  // 15 + GROUP - 1

__device__ __forceinline__ void gl_lds16(float* lds, const float* g) {
    __builtin_amdgcn_global_load_lds(
        (const __attribute__((address_space(1))) void*)g,
        (__attribute__((address_space(3))) void*)lds, 16, 0, 0);
}
__device__ __forceinline__ void gl_lds4(float* lds, const float* g) {
    __builtin_amdgcn_global_load_lds(
        (const __attribute__((address_space(1))) void*)g,
        (__attribute__((address_space(3))) void*)lds, 4, 0, 0);
}

__global__ __launch_bounds__(NT, 3) void multibox_kernel(
    const float* __restrict__ x, const float* __restrict__ base,
    float* __restrict__ out)
{
    __shared__ float buf[2][GROUP][LW];   // 16,896 B

    const int t  = threadIdx.x;
    const int w  = t >> 6;                // wave id (0..1)
    const int l  = t & 63;                // lane
    const int c0 = blockIdx.x * COLS;
    const int i0 = blockIdx.y * SR;
    const int j  = c0 + 4 * t;            // lane's first output column

    const float w3  = 1.f/(7.f*9.f);
    const float w5  = 1.f/(7.f*25.f);
    const float w7  = 1.f/(7.f*49.f);
    const float w9  = 1.f/(7.f*81.f);
    const float w11 = 1.f/(7.f*121.f);
    const float w13 = 1.f/(7.f*169.f);
    const float w15 = 1.f/(7.f*225.f);

    // Exact-edge 4-op DMA per row (float f <-> col c0-8+f, f = 0..527):
    //  L : f 0..63    4B/lane x64, per-lane clamp -> exact edge replicate
    //  M1: f 64..319  16B/lane x64, cols c0+56..c0+311 always in-range
    //  M2: f 320..511 16B/lane, lanes 0..47, cols <= c0+503 in-range
    //  R : f 512..527 4B/lane, lanes 0..15, per-lane clamp -> exact replicate
    const int colL  = min(max(c0 -   8 +     l, 0), W - 1);
    const int colM1 =         c0 +  56 + 4 * l;
    const int colM2 =         c0 + 312 + 4 * l;
    const int colR  = min(    c0 + 504 +     l,     W - 1);

    // wave w stages rows {w, w+2} of group g into slot b: 8 DMA ops/wave
    auto stage = [&](int g, int b) {
#pragma unroll
        for (int k = 0; k < 2; ++k) {
            const int rr = w + 2 * k;
            const int rc = min(max(i0 - RAD + g * GROUP + rr, 0), H - 1);
            const float* rp = x + (size_t)rc * W;
            float* lb = &buf[b][rr][0];
            gl_lds4(lb, rp + colL);
            gl_lds16(lb + 64, rp + colM1);
            if (l < 48) gl_lds16(lb + 320, rp + colM2);
            if (l < 16) gl_lds4 (lb + 512, rp + colR);
        }
    };

    // Two pending streams: A = cols (j, j+1), B = cols (j+2, j+3).
    // Pnd*[p] accumulates output row (i0 + 4g - 14 + p) before group g.
    // rr / p compile-time (inner unrolls); g stays RUNTIME (rounds 4/7 lesson).
    f32x2 PndA[PEND], PndB[PEND];
#pragma unroll
    for (int q = 0; q < PEND; ++q) { PndA[q] = f32x2{0.f, 0.f}; PndB[q] = f32x2{0.f, 0.f}; }

    auto compute_group = [&](int b, int g) {
#pragma unroll
        for (int rr = 0; rr < GROUP; ++rr) {
            if (g * GROUP + rr < NSTAGE) {
                // window floats f[0..19] <-> cols j-8 .. j+11, via 5x b128
                const float* p = &buf[b][rr][4 * t];
                float4 v0 = *(const float4*)(p);
                float4 v1 = *(const float4*)(p + 4);
                float4 v2 = *(const float4*)(p + 8);
                float4 v3 = *(const float4*)(p + 12);
                float4 v4 = *(const float4*)(p + 16);
                float f[20];
                f[0]=v0.x; f[1]=v0.y; f[2]=v0.z; f[3]=v0.w;
                f[4]=v1.x; f[5]=v1.y; f[6]=v1.z; f[7]=v1.w;
                f[8]=v2.x; f[9]=v2.y; f[10]=v2.z; f[11]=v2.w;
                f[12]=v3.x; f[13]=v3.y; f[14]=v3.z; f[15]=v3.w;
                f[16]=v4.x; f[17]=v4.y; f[18]=v4.z; f[19]=v4.w;

                auto PA = [&](int a) -> f32x2 {   // {f[a], f[a+1]}, a static
                    f32x2 r; r.x = f[a]; r.y = f[a + 1]; return r;
                };

                // stream A (cols j, j+1)
                f32x2 sA3  = PA(7) + PA(8) + PA(9);
                f32x2 sA5  = sA3  + PA(6) + PA(10);
                f32x2 sA7  = sA5  + PA(5) + PA(11);
                f32x2 sA9  = sA7  + PA(4) + PA(12);
                f32x2 sA11 = sA9  + PA(3) + PA(13);
                f32x2 sA13 = sA11 + PA(2) + PA(14);
                f32x2 sA15 = sA13 + PA(1) + PA(15);
                // stream B (cols j+2, j+3): PB(a) = PA(a+2)
                f32x2 sB3  = PA(9)  + PA(10) + PA(11);
                f32x2 sB5  = sB3  + PA(8) + PA(12);
                f32x2 sB7  = sB5  + PA(7) + PA(13);
                f32x2 sB9  = sB7  + PA(6) + PA(14);
                f32x2 sB11 = sB9  + PA(5) + PA(15);
                f32x2 sB13 = sB11 + PA(4) + PA(16);
                f32x2 sB15 = sB13 + PA(3) + PA(17);

                f32x2 cA7 = f32x2{w15, w15} * sA15;
                f32x2 cA6 = cA7 + f32x2{w13, w13} * sA13;
                f32x2 cA5 = cA6 + f32x2{w11, w11} * sA11;
                f32x2 cA4 = cA5 + f32x2{w9 , w9 } * sA9;
                f32x2 cA3 = cA4 + f32x2{w7 , w7 } * sA7;
                f32x2 cA2 = cA3 + f32x2{w5 , w5 } * sA5;
                f32x2 cA1 = cA2 + f32x2{w3 , w3 } * sA3;
                f32x2 cB7 = f32x2{w15, w15} * sB15;
                f32x2 cB6 = cB7 + f32x2{w13, w13} * sB13;
                f32x2 cB5 = cB6 + f32x2{w11, w11} * sB11;
                f32x2 cB4 = cB5 + f32x2{w9 , w9 } * sB9;
                f32x2 cB3 = cB4 + f32x2{w7 , w7 } * sB7;
                f32x2 cB2 = cB3 + f32x2{w5 , w5 } * sB5;
                f32x2 cB1 = cB2 + f32x2{w3 , w3 } * sB3;

                PndA[rr +  0] += cA7; PndA[rr +  1] += cA6; PndA[rr +  2] += cA5;
                PndA[rr +  3] += cA4; PndA[rr +  4] += cA3; PndA[rr +  5] += cA2;
                PndA[rr +  6] += cA1; PndA[rr +  7] += cA1; PndA[rr +  8] += cA1;
                PndA[rr +  9] += cA2; PndA[rr + 10] += cA3; PndA[rr + 11] += cA4;
                PndA[rr + 12] += cA5; PndA[rr + 13] += cA6; PndA[rr + 14] += cA7;
                PndB[rr +  0] += cB7; PndB[rr +  1] += cB6; PndB[rr +  2] += cB5;
                PndB[rr +  3] += cB4; PndB[rr +  4] += cB3; PndB[rr +  5] += cB2;
                PndB[rr +  6] += cB1; PndB[rr +  7] += cB1; PndB[rr +  8] += cB1;
                PndB[rr +  9] += cB2; PndB[rr + 10] += cB3; PndB[rr + 11] += cB4;
                PndB[rr + 12] += cB5; PndB[rr + 13] += cB6; PndB[rr + 14] += cB7;
            }
        }

        // emit completed rows with float4 load/store (16B/lane)
#pragma unroll
        for (int p = 0; p < GROUP; ++p) {
            const int o_ofs = 4 * g - 14 + p;
            if (o_ofs >= 0 && o_ofs < SR) {
                const size_t bi = (size_t)(i0 + o_ofs) * W + j;
                float4 bm = *(const float4*)(base + bi);
                float4 ov;
                ov.x = PndA[p].x * bm.x;
                ov.y = PndA[p].y * bm.y;
                ov.z = PndB[p].x * bm.z;
                ov.w = PndB[p].y * bm.w;
                *(float4*)(out + bi) = ov;
            }
        }

        // shift both windows by GROUP (static indices)
#pragma unroll
        for (int p = 0; p < PEND - GROUP; ++p) { PndA[p] = PndA[p + GROUP]; PndB[p] = PndB[p + GROUP]; }
#pragma unroll
        for (int p = PEND - GROUP; p < PEND; ++p) { PndA[p] = f32x2{0.f, 0.f}; PndB[p] = f32x2{0.f, 0.f}; }
    };

    stage(0, 0);
    __syncthreads();

    // MUST stay rolled (round-7 lesson: unroll hoists loads -> spill)
#pragma clang loop unroll(disable)
    for (int g = 0; g < NG - 1; ++g) {
        stage(g + 1, (g + 1) & 1);   // issue next group's 8 DMA ops early
        compute_group(g & 1, g);     // ds_read_b128 + VALU + float4 emit
        __syncthreads();             // next group's rows landed
    }
    compute_group((NG - 1) & 1, NG - 1);
}

extern "C" void kernel_launch(void* const* d_in, const int* in_sizes, int n_in,
                              void* d_out, int out_size, void* d_ws, size_t ws_size,
                              hipStream_t stream) {
    const float* x    = (const float*)d_in[0];
    const float* base = (const float*)d_in[1];
    float* out        = (float*)d_out;

    dim3 grid(W / COLS, H / SR);   // (8, 256) = 2048 blocks, 2 waves each
    multibox_kernel<<<grid, dim3(NT), 0, stream>>>(x, base, out);
}